// Round 7
// baseline (356.672 us; speedup 1.0000x reference)
//
#include <hip/hip_runtime.h>
#include <math.h>

// B=2, L=2048, H=8, E=64. Outputs: V [B,L,H,E] then SA [B,H,L,S], fp32.
#define L_DIM 2048
#define H_DIM 8
#define ROWSTRIDE 512                 // H*E floats between consecutive l
#define NT 512
// 0.125 * log2(e): scores computed in log2 domain -> raw v_exp_f32 for softmax
#define QSCALE 0.18033688011112042f

typedef __attribute__((ext_vector_type(8))) short short8;
typedef __attribute__((ext_vector_type(4))) float floatx4;

__device__ __forceinline__ float fexp2(float x) {
#if __has_builtin(__builtin_amdgcn_exp2f)
    return __builtin_amdgcn_exp2f(x);   // raw v_exp_f32
#else
    return exp2f(x);
#endif
}

__device__ __forceinline__ float flog2(float x) {
#if __has_builtin(__builtin_amdgcn_logf)
    return __builtin_amdgcn_logf(x);    // raw v_log_f32 (base-2)
#else
    return log2f(x);
#endif
}

// packed fp32x2 -> bf16x2 (RNE), one VALU op for two elements
__device__ __forceinline__ unsigned int cvtpk(float lo, float hi) {
    unsigned int r;
    asm("v_cvt_pk_bf16_f32 %0, %1, %2" : "=v"(r) : "v"(lo), "v"(hi));
    return r;
}

__device__ __forceinline__ short8 pack8(float4 a, float4 b) {
    union { unsigned int u[4]; short8 v; } pk;
    pk.u[0] = cvtpk(a.x, a.y); pk.u[1] = cvtpk(a.z, a.w);
    pk.u[2] = cvtpk(b.x, b.y); pk.u[3] = cvtpk(b.z, b.w);
    return pk.v;
}

__device__ __forceinline__ short8 pack8q(float4 a, float4 b) {
    union { unsigned int u[4]; short8 v; } pk;
    pk.u[0] = cvtpk(a.x * QSCALE, a.y * QSCALE);
    pk.u[1] = cvtpk(a.z * QSCALE, a.w * QSCALE);
    pk.u[2] = cvtpk(b.x * QSCALE, b.y * QSCALE);
    pk.u[3] = cvtpk(b.z * QSCALE, b.w * QSCALE);
    return pk.v;
}

// Swizzled short-index within a [64][64] bf16 tile. Rows are 128B = 8 x 16B
// blocks; phys block = logical block ^ (row&7). Preserves col&7 (b32/b128
// alignment holds). Bijective per row.
__device__ __forceinline__ int swz(int row, int col) {
    return (row << 6) + ((((col >> 3) ^ (row & 7)) << 3) | (col & 7));
}

// ROUND 6/7: swapped QK^T (mfma(K,Q)) makes each lane own ONE q-row with 8
// CONSECUTIVE s-columns -> P goes to the PV A-fragment entirely in-register
// (4 cvtpk), eliminating the Ps LDS write->lgkmcnt->read chain. Max-tracking
// dropped (scores in log2 domain are |v|<~30 << 127 for any plausible data:
// exp2 can't overflow fp32); pass 1 is a per-lane scalar l += sum(exp2(v)),
// merged with 2 shfl rounds; c = log2(l) folds normalization exactly as
// before. SA stores: 2x dwordx4 per lane (32B contiguous).
// K staging row-permute: phys s-row (g:1|q2:2|u:1|r:2 bits) stored at LDS row
// (g:1|u:1|q2:2|r:2), so A-fragment sub-tile u, A-row rho=quad*4+r holds
// s = 32g + quad*8 + u*4 + r -> lane's 8 QK outputs are s = base..base+7 and
// equal the PV k-slots quad*8..quad*8+7 (V^T staging stays linear).
// Mapping/grid unchanged from round 5 (dual-robust complementary pairs).
__global__ __launch_bounds__(NT, 4)
void attn_mfma8(const float* __restrict__ Q, const float* __restrict__ K,
                const float* __restrict__ Vv, float* __restrict__ outV,
                float* __restrict__ outSA)
{
    __shared__ __align__(16) unsigned char smem[33792];
    unsigned short* Ks = (unsigned short*)(smem);           // [2 buf][64][64] swz, row-permuted s
    unsigned short* Vt = (unsigned short*)(smem + 16384);   // [2 buf][64][64] swz, row=e col=s
    float* Ll = (float*)(smem + 32768);                     // [2][64]
    float* Ob = (float*)(smem);                             // [64][65] fp32, overlays Ks/Vt head

    const int t    = threadIdx.x;
    const int lane = t & 63;
    const int w    = t >> 6;           // wave 0..7
    const int g    = w >> 2;           // s-column group: cols [32g, 32g+32)
    const int wg   = w & 3;            // wave-in-group: q-rows 16wg..16wg+15
    const int l15  = lane & 15;
    const int quad = lane >> 4;
    const int gc   = g << 5;           // group column base within tile

    const int bid = blockIdx.x;
    const int h   = bid & 7;
    const int b   = (bid >> 3) & 1;
    const int kk  = bid >> 4;                   // 0..31
    const int qm  = (kk < 16) ? kk : (47 - kk); // bijective, qm(k)+qm(k+16)=31
    const int qt  = b ? (31 - qm) : qm;
    const int q0  = qt << 6;
    const int ntiles = qt + 1;

    const float* Qb = Q  + (size_t)b * L_DIM * ROWSTRIDE + h * 64;
    const float* Kb = K  + (size_t)b * L_DIM * ROWSTRIDE + h * 64;
    const float* Vb = Vv + (size_t)b * L_DIM * ROWSTRIDE + h * 64;
    float* saBase = outSA + (size_t)(b * H_DIM + h) * L_DIM * L_DIM;

    // ---- K staging map: thread handles phys s-row sr, 8 e at col sc.
    // sr bits [4:3]=q2, [2]=u, [1:0]=r -> LDS row bits [4]=u, [3:2]=q2, [1:0]=r.
    const int sr = t >> 3, sc = (t & 7) << 3;
    const int kpr = (sr & 32) | ((sr & 4) << 2) | ((sr >> 1) & 12) | (sr & 3);
    const int kswz = swz(kpr, sc);     // 16B-aligned short8 dest

    // ---- V staging map: thread handles s-rows {2rp, 2rp+1}, 4 e at ec.
    const int rp = t >> 4, ec = (t & 15) << 2;
    const int vswz0 = swz(ec + 0, 2 * rp);   // b32-aligned (col even)
    const int vswz1 = swz(ec + 1, 2 * rp);
    const int vswz2 = swz(ec + 2, 2 * rp);
    const int vswz3 = swz(ec + 3, 2 * rp);

    auto stageK = [&](int bufi, float4 f0, float4 f1) {
        *(short8*)&Ks[(bufi << 12) + kswz] = pack8(f0, f1);
    };
    auto stageV = [&](int bufi, float4 a, float4 bb) {
        unsigned short* Vn = Vt + (bufi << 12);
        *(unsigned int*)&Vn[vswz0] = cvtpk(a.x, bb.x);
        *(unsigned int*)&Vn[vswz1] = cvtpk(a.y, bb.y);
        *(unsigned int*)&Vn[vswz2] = cvtpk(a.z, bb.z);
        *(unsigned int*)&Vn[vswz3] = cvtpk(a.w, bb.w);
    };

    // ---- Q fragments straight from global (scale folded); used as B-operand ----
    short8 bQ0, bQ1;
    {
        const float* qsrc = Qb + (size_t)(q0 + 16 * wg + l15) * ROWSTRIDE + quad * 8;
        bQ0 = pack8q(*(const float4*)(qsrc),      *(const float4*)(qsrc + 4));
        bQ1 = pack8q(*(const float4*)(qsrc + 32), *(const float4*)(qsrc + 36));
    }

    const int qrow = q0 + 16 * wg + l15;    // this lane's q-row (both passes)

    // QK for this group's 32 s-cols: d0 -> s = tile_s0+gc+quad*8+{0..3},
    // d1 -> +{4..7}  (via the K row-permute)
    auto computeQK = [&](const unsigned short* Kc, floatx4& d0, floatx4& d1) {
        short8 a00 = *(const short8*)&Kc[swz(gc + l15, quad * 8)];
        short8 a01 = *(const short8*)&Kc[swz(gc + l15, 32 + quad * 8)];
        short8 a10 = *(const short8*)&Kc[swz(gc + 16 + l15, quad * 8)];
        short8 a11 = *(const short8*)&Kc[swz(gc + 16 + l15, 32 + quad * 8)];
        floatx4 z = {0.f, 0.f, 0.f, 0.f};
        d0 = __builtin_amdgcn_mfma_f32_16x16x32_bf16(a01, bQ1,
             __builtin_amdgcn_mfma_f32_16x16x32_bf16(a00, bQ0, z, 0, 0, 0), 0, 0, 0);
        d1 = __builtin_amdgcn_mfma_f32_16x16x32_bf16(a11, bQ1,
             __builtin_amdgcn_mfma_f32_16x16x32_bf16(a10, bQ0, z, 0, 0, 0), 0, 0, 0);
    };

    // =================== PASS 1: row denom (no max; per-lane scalar) ===================
    float l_acc = 0.f;
    {   // prologue: stage K tile 0 into buf 0
        const float* src = Kb + (size_t)sr * ROWSTRIDE + sc;
        stageK(0, *(const float4*)src, *(const float4*)(src + 4));
    }
    __syncthreads();

    for (int st = 0; st < ntiles; ++st) {
        const int cur = st & 1;
        const int stp = (st + 1 < ntiles) ? (st + 1) : st;
        const float* ksrc = Kb + (size_t)((stp << 6) + sr) * ROWSTRIDE + sc;
        float4 kf0 = *(const float4*)(ksrc);
        float4 kf1 = *(const float4*)(ksrc + 4);

        floatx4 d0, d1;
        computeQK(Ks + (cur << 12), d0, d1);

        if (st == qt) {          // diagonal tile: masked terms contribute 0
            const int sb = (st << 6) + gc + quad * 8;
            float es = 0.f;
#pragma unroll
            for (int r = 0; r < 4; ++r) es += (sb + r     <= qrow) ? fexp2(d0[r]) : 0.f;
#pragma unroll
            for (int r = 0; r < 4; ++r) es += (sb + 4 + r <= qrow) ? fexp2(d1[r]) : 0.f;
            l_acc += es;
        } else {
            float e0 = fexp2(d0[0]) + fexp2(d0[1]);
            float e1 = fexp2(d0[2]) + fexp2(d0[3]);
            float e2 = fexp2(d1[0]) + fexp2(d1[1]);
            float e3 = fexp2(d1[2]) + fexp2(d1[3]);
            l_acc += (e0 + e1) + (e2 + e3);
        }

        if (st + 1 < ntiles) stageK(cur ^ 1, kf0, kf1);
        __syncthreads();
    }

    // merge across the 4 quads covering this q-row's group columns
    l_acc += __shfl_xor(l_acc, 16);
    l_acc += __shfl_xor(l_acc, 32);

    // cross-group combine via LDS; pass-2 tile-0 staging overlaps it
    if (quad == 0) Ll[g * 64 + 16 * wg + l15] = l_acc;
    {
        const float* src = Kb + (size_t)sr * ROWSTRIDE + sc;
        stageK(0, *(const float4*)src, *(const float4*)(src + 4));
        const float* vsrc = Vb + (size_t)(2 * rp) * ROWSTRIDE + ec;
        stageV(0, *(const float4*)vsrc, *(const float4*)(vsrc + ROWSTRIDE));
    }
    __syncthreads();

    // c_row = log2(l_total): p = exp2(v - c_row), normalization exactly folded
    const float c_row = flog2(Ll[16 * wg + l15] + Ll[64 + 16 * wg + l15]);

    // =================== PASS 2: SA write + PV ===================
    floatx4 oacc[4];
#pragma unroll
    for (int j = 0; j < 4; ++j) oacc[j] = (floatx4){0.f, 0.f, 0.f, 0.f};

    for (int st = 0; st < ntiles; ++st) {
        const int cur = st & 1;
        const int stp = (st + 1 < ntiles) ? (st + 1) : st;
        const float* ksrc = Kb + (size_t)((stp << 6) + sr) * ROWSTRIDE + sc;
        const float* vsrc = Vb + (size_t)((stp << 6) + 2 * rp) * ROWSTRIDE + ec;
        float4 kf0 = *(const float4*)(ksrc);
        float4 kf1 = *(const float4*)(ksrc + 4);
        float4 vf0 = *(const float4*)(vsrc);
        float4 vf1 = *(const float4*)(vsrc + ROWSTRIDE);

        floatx4 d0, d1;
        computeQK(Ks + (cur << 12), d0, d1);

        const int sb = (st << 6) + gc + quad * 8;
        float p0, p1, p2, p3, p4, p5, p6, p7;
        if (st == qt) {          // diagonal tile: masked path
            p0 = (sb + 0 <= qrow) ? fexp2(d0[0] - c_row) : 0.f;
            p1 = (sb + 1 <= qrow) ? fexp2(d0[1] - c_row) : 0.f;
            p2 = (sb + 2 <= qrow) ? fexp2(d0[2] - c_row) : 0.f;
            p3 = (sb + 3 <= qrow) ? fexp2(d0[3] - c_row) : 0.f;
            p4 = (sb + 4 <= qrow) ? fexp2(d1[0] - c_row) : 0.f;
            p5 = (sb + 5 <= qrow) ? fexp2(d1[1] - c_row) : 0.f;
            p6 = (sb + 6 <= qrow) ? fexp2(d1[2] - c_row) : 0.f;
            p7 = (sb + 7 <= qrow) ? fexp2(d1[3] - c_row) : 0.f;
        } else {
            p0 = fexp2(d0[0] - c_row); p1 = fexp2(d0[1] - c_row);
            p2 = fexp2(d0[2] - c_row); p3 = fexp2(d0[3] - c_row);
            p4 = fexp2(d1[0] - c_row); p5 = fexp2(d1[1] - c_row);
            p6 = fexp2(d1[2] - c_row); p7 = fexp2(d1[3] - c_row);
        }
        {   // SA: lane writes its q-row's 8 consecutive cols (32B)
            float* sap = saBase + (size_t)qrow * L_DIM + sb;
            float4 w0; w0.x = p0; w0.y = p1; w0.z = p2; w0.w = p3;
            float4 w1; w1.x = p4; w1.y = p5; w1.z = p6; w1.w = p7;
            *(float4*)(sap)     = w0;
            *(float4*)(sap + 4) = w1;
        }
        // PV A-fragment built in-register: k-slot quad*8+j <-> s-col sb+j
        union { unsigned int u[4]; short8 v; } ap;
        ap.u[0] = cvtpk(p0, p1); ap.u[1] = cvtpk(p2, p3);
        ap.u[2] = cvtpk(p4, p5); ap.u[3] = cvtpk(p6, p7);
        const unsigned short* Vc = Vt + (cur << 12);
#pragma unroll
        for (int j = 0; j < 4; ++j) {
            short8 bv = *(const short8*)&Vc[swz(16 * j + l15, gc + quad * 8)];
            oacc[j] = __builtin_amdgcn_mfma_f32_16x16x32_bf16(ap.v, bv, oacc[j], 0, 0, 0);
        }

        if (st + 1 < ntiles) { stageK(cur ^ 1, kf0, kf1); stageV(cur ^ 1, vf0, vf1); }
        __syncthreads();
    }

    // ---- combine partial O across groups (Ob overlays Ks/Vt; safe after barrier) ----
    if (g == 1) {
#pragma unroll
        for (int r = 0; r < 4; ++r) {
            const int row = 16 * wg + quad * 4 + r;
#pragma unroll
            for (int j = 0; j < 4; ++j)
                Ob[row * 65 + 16 * j + l15] = oacc[j][r];
        }
    }
    __syncthreads();
    if (g == 0) {
#pragma unroll
        for (int r = 0; r < 4; ++r) {
            const int row = 16 * wg + quad * 4 + r;
            float* op = outV + ((size_t)b * L_DIM + q0 + row) * ROWSTRIDE + h * 64 + l15;
#pragma unroll
            for (int j = 0; j < 4; ++j)
                op[16 * j] = oacc[j][r] + Ob[row * 65 + 16 * j + l15];
        }
    }

    // ---- zero-fill SA above the diagonal tile (d_out is poisoned) ----
    {
        const int z0 = ntiles << 6;
        const int zr = t >> 3;               // 64 rows, 8 threads/row
        float* rowp = saBase + (size_t)(q0 + zr) * L_DIM;
        const float4 zf = {0.f, 0.f, 0.f, 0.f};
        for (int s = z0 + (t & 7) * 4; s < L_DIM; s += 32)
            *(float4*)(rowp + s) = zf;
    }
}

extern "C" void kernel_launch(void* const* d_in, const int* in_sizes, int n_in,
                              void* d_out, int out_size, void* d_ws, size_t ws_size,
                              hipStream_t stream) {
    const float* Q  = (const float*)d_in[0];
    const float* K  = (const float*)d_in[1];
    const float* Vv = (const float*)d_in[2];
    float* out   = (float*)d_out;
    float* outV  = out;                                       // [B,L,H,E]
    float* outSA = out + (size_t)2 * L_DIM * H_DIM * 64;      // [B,H,L,S]

    dim3 grid(512);   // complementary q-tile pairs (dual-robust decode)
    dim3 block(NT);
    attn_mfma8<<<grid, block, 0, stream>>>(Q, K, Vv, outV, outSA);
}

// Round 8
// 354.603 us; speedup vs baseline: 1.0058x; 1.0058x over previous
//
#include <hip/hip_runtime.h>
#include <math.h>

// B=2, L=2048, H=8, E=64. Outputs: V [B,L,H,E] then SA [B,H,L,S], fp32.
#define L_DIM 2048
#define H_DIM 8
#define ROWSTRIDE 512                 // H*E floats between consecutive l
// 0.125 * log2(e): scores computed in log2 domain -> raw v_exp_f32 for softmax
#define QSCALE 0.18033688011112042f

typedef __attribute__((ext_vector_type(8))) short short8;
typedef __attribute__((ext_vector_type(4))) float floatx4;

__device__ __forceinline__ float fexp2(float x) {
#if __has_builtin(__builtin_amdgcn_exp2f)
    return __builtin_amdgcn_exp2f(x);   // raw v_exp_f32
#else
    return exp2f(x);
#endif
}

__device__ __forceinline__ float flog2(float x) {
#if __has_builtin(__builtin_amdgcn_logf)
    return __builtin_amdgcn_logf(x);    // raw v_log_f32 (base-2)
#else
    return log2f(x);
#endif
}

// packed fp32x2 -> bf16x2 (RNE), one VALU op for two elements
__device__ __forceinline__ unsigned int cvtpk(float lo, float hi) {
    unsigned int r;
    asm("v_cvt_pk_bf16_f32 %0, %1, %2" : "=v"(r) : "v"(lo), "v"(hi));
    return r;
}

__device__ __forceinline__ short8 pack8(float4 a, float4 b) {
    union { unsigned int u[4]; short8 v; } pk;
    pk.u[0] = cvtpk(a.x, a.y); pk.u[1] = cvtpk(a.z, a.w);
    pk.u[2] = cvtpk(b.x, b.y); pk.u[3] = cvtpk(b.z, b.w);
    return pk.v;
}

__device__ __forceinline__ short8 pack8q(float4 a, float4 b) {
    union { unsigned int u[4]; short8 v; } pk;
    pk.u[0] = cvtpk(a.x * QSCALE, a.y * QSCALE);
    pk.u[1] = cvtpk(a.z * QSCALE, a.w * QSCALE);
    pk.u[2] = cvtpk(b.x * QSCALE, b.y * QSCALE);
    pk.u[3] = cvtpk(b.z * QSCALE, b.w * QSCALE);
    return pk.v;
}

// Swizzled short-index within a [64][64] bf16 tile. Rows are 128B = 8 x 16B
// blocks; phys block = logical block ^ (row&7). Preserves col&7 (b32/b128
// alignment holds). Bijective per row.
__device__ __forceinline__ int swz(int row, int col) {
    return (row << 6) + ((((col >> 3) ^ (row & 7)) << 3) | (col & 7));
}

// Barrier WITHOUT vmcnt(0) drain: __syncthreads() emits s_waitcnt vmcnt(0)
// lgkmcnt(0) + s_barrier, draining SA-store acks every phase for nothing
// (global stores never need block ordering). LDS producer/consumer hazards
// are fully lgkm-tracked; prefetch-load vmcnt waits are compiler-inserted at
// the stage-write uses (before this barrier). m201-proven pattern.
__device__ __forceinline__ void sbar() {
    asm volatile("s_waitcnt lgkmcnt(0)" ::: "memory");
    __builtin_amdgcn_s_barrier();
    asm volatile("" ::: "memory");
}

// Shared block decode: XCD bid&7 hosts head h (both batches: 2MB K+V
// L2-resident). qmap keeps q-tile pairs complementary under both (m,m+1)
// and (m,m+32) co-residency (round-5, verified-neutral-or-better).
#define DECODE_BLOCK()                                            \
    const int bid = blockIdx.x;                                   \
    const int h   = bid & 7;                                      \
    const int b   = (bid >> 3) & 1;                               \
    const int kk  = bid >> 4;                                     \
    const int qm  = (kk < 16) ? kk : (47 - kk);                   \
    const int qt  = b ? (31 - qm) : qm;                           \
    const int q0  = qt << 6;                                      \
    const int ntiles = qt + 1;

// ======================= PASS-1 KERNEL: row log-sum-exp =======================
// Writes lse[(b*8+h)*2048 + l] = log2( sum_{s<=l} exp2(score) ) for all rows.
// No-max softmax verified safe in round 7 (log2-domain scores << 127).
// 512 blocks x 256 threads (4 waves, 16 q-rows each); K dbuf staging only.
__global__ __launch_bounds__(256, 4)
void attn_lse9(const float* __restrict__ Q, const float* __restrict__ K,
               float* __restrict__ lse)
{
    __shared__ __align__(16) unsigned short Ks[2][4096];   // [buf][64][64] swz

    const int t    = threadIdx.x;
    const int lane = t & 63;
    const int w    = t >> 6;           // wave 0..3: q-rows 16w..16w+15
    const int l15  = lane & 15;
    const int quad = lane >> 4;

    DECODE_BLOCK();

    const float* Qb = Q + (size_t)b * L_DIM * ROWSTRIDE + h * 64;
    const float* Kb = K + (size_t)b * L_DIM * ROWSTRIDE + h * 64;
    float* lout = lse + (size_t)(b * H_DIM + h) * L_DIM;

    // staging: thread t handles s-row sr, 16 elems at col sc (2 x short8)
    const int sr = t >> 2, sc = (t & 3) << 4;
    const int ksz0 = swz(sr, sc), ksz1 = swz(sr, sc + 8);

    // Q fragment (A-operand; scale folded)
    short8 aQ0, aQ1;
    {
        const float* qsrc = Qb + (size_t)(q0 + 16 * w + l15) * ROWSTRIDE + quad * 8;
        aQ0 = pack8q(*(const float4*)(qsrc),      *(const float4*)(qsrc + 4));
        aQ1 = pack8q(*(const float4*)(qsrc + 32), *(const float4*)(qsrc + 36));
    }

    float l_r[4] = {0.f, 0.f, 0.f, 0.f};

    {   // prologue: stage tile 0
        const float* src = Kb + (size_t)sr * ROWSTRIDE + sc;
        *(short8*)&Ks[0][ksz0] = pack8(*(const float4*)(src),     *(const float4*)(src + 4));
        *(short8*)&Ks[0][ksz1] = pack8(*(const float4*)(src + 8), *(const float4*)(src + 12));
    }
    sbar();

    for (int st = 0; st < ntiles; ++st) {
        const int cur = st & 1;
        const int stp = (st + 1 < ntiles) ? (st + 1) : st;
        const float* ksrc = Kb + (size_t)((stp << 6) + sr) * ROWSTRIDE + sc;
        float4 f0 = *(const float4*)(ksrc);
        float4 f1 = *(const float4*)(ksrc + 4);
        float4 f2 = *(const float4*)(ksrc + 8);
        float4 f3 = *(const float4*)(ksrc + 12);

#pragma unroll
        for (int jj = 0; jj < 4; ++jj) {
            short8 b0 = *(const short8*)&Ks[cur][swz(16 * jj + l15, quad * 8)];
            short8 b1 = *(const short8*)&Ks[cur][swz(16 * jj + l15, 32 + quad * 8)];
            floatx4 z = {0.f, 0.f, 0.f, 0.f};
            floatx4 d = __builtin_amdgcn_mfma_f32_16x16x32_bf16(aQ1, b1,
                        __builtin_amdgcn_mfma_f32_16x16x32_bf16(aQ0, b0, z, 0, 0, 0), 0, 0, 0);
            if (st == qt) {      // diagonal tile: masked terms contribute 0
                const int scol = (st << 6) + 16 * jj + l15;
#pragma unroll
                for (int r = 0; r < 4; ++r)
                    l_r[r] += (scol <= q0 + 16 * w + quad * 4 + r) ? fexp2(d[r]) : 0.f;
            } else {
#pragma unroll
                for (int r = 0; r < 4; ++r) l_r[r] += fexp2(d[r]);
            }
        }

        if (st + 1 < ntiles) {
            *(short8*)&Ks[cur ^ 1][ksz0] = pack8(f0, f1);
            *(short8*)&Ks[cur ^ 1][ksz1] = pack8(f2, f3);
        }
        sbar();
    }

    // merge across the 16 l15-lanes of each quad (cols), then write c = log2(l)
#pragma unroll
    for (int r = 0; r < 4; ++r) {
#pragma unroll
        for (int mk = 1; mk < 16; mk <<= 1) l_r[r] += __shfl_xor(l_r[r], mk);
    }
    if (l15 == 0) {
#pragma unroll
        for (int r = 0; r < 4; ++r)
            lout[q0 + 16 * w + quad * 4 + r] = flog2(l_r[r]);
    }
}

// ======================= PASS-2 KERNEL: SA write + PV =======================
// Round-5 pass-2 verbatim (proven layout: coalesced 128B SA runs, Ps
// roundtrip, s-pairing K permute, 2-tile phases), minus pass 1 (c_r read
// from lse as one float4), with sbar() barriers.
__global__ __launch_bounds__(512, 4)
void attn_pv9(const float* __restrict__ Q, const float* __restrict__ K,
              const float* __restrict__ Vv, float* __restrict__ outV,
              float* __restrict__ outSA, const float* __restrict__ lse)
{
    __shared__ __align__(16) unsigned char smem[73728];
    unsigned short* Ks = (unsigned short*)(smem);           // [4 buf][64][64] swz, row-permuted s
    unsigned short* Vt = (unsigned short*)(smem + 32768);   // [4 buf][64][64] swz, row=e col=s
    unsigned short* Ps = (unsigned short*)(smem + 65536);   // [64][64] swz
    float* Ob = (float*)(smem);                             // [64][65] fp32, overlays Ks

    const int t    = threadIdx.x;
    const int lane = t & 63;
    const int w    = t >> 6;           // wave 0..7
    const int g    = w >> 2;           // s-column group: cols [32g, 32g+32)
    const int wg   = w & 3;            // wave-in-group: q-rows 16wg..16wg+15
    const int l15  = lane & 15;
    const int quad = lane >> 4;
    const int gc   = g << 5;

    DECODE_BLOCK();
    const int nphase = (ntiles + 1) >> 1;

    const float* Qb = Q  + (size_t)b * L_DIM * ROWSTRIDE + h * 64;
    const float* Kb = K  + (size_t)b * L_DIM * ROWSTRIDE + h * 64;
    const float* Vb = Vv + (size_t)b * L_DIM * ROWSTRIDE + h * 64;
    float* saBase = outSA + (size_t)(b * H_DIM + h) * L_DIM * L_DIM;

    // c_r for this lane's 4 q-rows (consecutive, 16B-aligned) from pass 1
    float c_r[4];
    {
        const float4 cv = *(const float4*)(lse + (size_t)(b * H_DIM + h) * L_DIM
                                           + q0 + 16 * wg + quad * 4);
        c_r[0] = cv.x; c_r[1] = cv.y; c_r[2] = cv.z; c_r[3] = cv.w;
    }

    // K staging map (s-pairing row permute: frag jj, lane l15 <-> s-col 2*l15+jj)
    const int sr = t >> 3, sc = (t & 7) << 3;
    const int kq = sr & 31;
    const int kpr = (sr & 32) | ((kq & 1) << 4) | (kq >> 1);
    const int kswz = swz(kpr, sc);

    // V staging map: thread handles s-rows {2rp, 2rp+1}, 4 e at ec
    const int rp = t >> 4, ec = (t & 15) << 2;
    const int vswz0 = swz(ec + 0, 2 * rp);
    const int vswz1 = swz(ec + 1, 2 * rp);
    const int vswz2 = swz(ec + 2, 2 * rp);
    const int vswz3 = swz(ec + 3, 2 * rp);

    auto stageK = [&](int bufi, float4 f0, float4 f1) {
        *(short8*)&Ks[(bufi << 12) + kswz] = pack8(f0, f1);
    };
    auto stageV = [&](int bufi, float4 a, float4 bb) {
        unsigned short* Vn = Vt + (bufi << 12);
        *(unsigned int*)&Vn[vswz0] = cvtpk(a.x, bb.x);
        *(unsigned int*)&Vn[vswz1] = cvtpk(a.y, bb.y);
        *(unsigned int*)&Vn[vswz2] = cvtpk(a.z, bb.z);
        *(unsigned int*)&Vn[vswz3] = cvtpk(a.w, bb.w);
    };

    // Q fragments (A-operand, scale folded)
    short8 aQ0, aQ1;
    {
        const float* qsrc = Qb + (size_t)(q0 + 16 * wg + l15) * ROWSTRIDE + quad * 8;
        aQ0 = pack8q(*(const float4*)(qsrc),      *(const float4*)(qsrc + 4));
        aQ1 = pack8q(*(const float4*)(qsrc + 32), *(const float4*)(qsrc + 36));
    }

    floatx4 oacc[4];
#pragma unroll
    for (int j = 0; j < 4; ++j) oacc[j] = (floatx4){0.f, 0.f, 0.f, 0.f};

    auto compute2 = [&](int bufi, int st) {
        const unsigned short* Kc = Ks + (bufi << 12);
        const unsigned short* Vc = Vt + (bufi << 12);
        floatx4 d0, d1;
        {
            short8 b0 = *(const short8*)&Kc[swz(gc + l15, quad * 8)];
            short8 b1 = *(const short8*)&Kc[swz(gc + l15, 32 + quad * 8)];
            floatx4 acc = {0.f, 0.f, 0.f, 0.f};
            acc = __builtin_amdgcn_mfma_f32_16x16x32_bf16(aQ0, b0, acc, 0, 0, 0);
            acc = __builtin_amdgcn_mfma_f32_16x16x32_bf16(aQ1, b1, acc, 0, 0, 0);
            d0 = acc;
        }
        {
            short8 b0 = *(const short8*)&Kc[swz(gc + 16 + l15, quad * 8)];
            short8 b1 = *(const short8*)&Kc[swz(gc + 16 + l15, 32 + quad * 8)];
            floatx4 acc = {0.f, 0.f, 0.f, 0.f};
            acc = __builtin_amdgcn_mfma_f32_16x16x32_bf16(aQ0, b0, acc, 0, 0, 0);
            acc = __builtin_amdgcn_mfma_f32_16x16x32_bf16(aQ1, b1, acc, 0, 0, 0);
            d1 = acc;
        }
        const int s0 = st << 6;
        const int scol = s0 + gc + 2 * l15;
        if (st == qt) {          // diagonal tile: masked path
#pragma unroll
            for (int r = 0; r < 4; ++r) {
                const int lrow = q0 + 16 * wg + quad * 4 + r;
                const float cr = c_r[r];
                float p0 = (scol     <= lrow) ? fexp2(d0[r] - cr) : 0.0f;
                float p1 = (scol + 1 <= lrow) ? fexp2(d1[r] - cr) : 0.0f;
                float2 pr; pr.x = p0; pr.y = p1;
                *(float2*)(saBase + (size_t)lrow * L_DIM + scol) = pr;
                *(unsigned int*)&Ps[swz(16 * wg + quad * 4 + r, gc + 2 * l15)] = cvtpk(p0, p1);
            }
        } else {                 // interior tile
#pragma unroll
            for (int r = 0; r < 4; ++r) {
                const int lrow = q0 + 16 * wg + quad * 4 + r;
                const float cr = c_r[r];
                float p0 = fexp2(d0[r] - cr);
                float p1 = fexp2(d1[r] - cr);
                float2 pr; pr.x = p0; pr.y = p1;
                *(float2*)(saBase + (size_t)lrow * L_DIM + scol) = pr;
                *(unsigned int*)&Ps[swz(16 * wg + quad * 4 + r, gc + 2 * l15)] = cvtpk(p0, p1);
            }
        }
        // PV over this group's 32 s-cols (Ps block is wave-private; in-order lgkmcnt covers RAW)
        short8 aP = *(const short8*)&Ps[swz(16 * wg + l15, gc + quad * 8)];
#pragma unroll
        for (int j = 0; j < 4; ++j) {
            short8 bv = *(const short8*)&Vc[swz(16 * j + l15, gc + quad * 8)];
            oacc[j] = __builtin_amdgcn_mfma_f32_16x16x32_bf16(aP, bv, oacc[j], 0, 0, 0);
        }
    };

    {   // prologue: stage K and V^T tiles 0,1 into bufs 0,1
        const int t1 = (ntiles > 1) ? 1 : 0;
        const float* k0 = Kb + (size_t)sr * ROWSTRIDE + sc;
        const float* k1 = Kb + (size_t)((t1 << 6) + sr) * ROWSTRIDE + sc;
        stageK(0, *(const float4*)k0, *(const float4*)(k0 + 4));
        stageK(1, *(const float4*)k1, *(const float4*)(k1 + 4));
        const float* v0p = Vb + (size_t)(2 * rp) * ROWSTRIDE + ec;
        const float* v1p = Vb + (size_t)((t1 << 6) + 2 * rp) * ROWSTRIDE + ec;
        stageV(0, *(const float4*)v0p, *(const float4*)(v0p + ROWSTRIDE));
        stageV(1, *(const float4*)v1p, *(const float4*)(v1p + ROWSTRIDE));
    }
    sbar();

    for (int ph = 0; ph < nphase; ++ph) {
        const int base = ph << 1;
        const int pb   = (ph & 1) << 1;
        const int t2 = (base + 2 < ntiles) ? base + 2 : ntiles - 1;
        const int t3 = (base + 3 < ntiles) ? base + 3 : ntiles - 1;
        const float* k2 = Kb + (size_t)((t2 << 6) + sr) * ROWSTRIDE + sc;
        const float* k3 = Kb + (size_t)((t3 << 6) + sr) * ROWSTRIDE + sc;
        const float* v2 = Vb + (size_t)((t2 << 6) + 2 * rp) * ROWSTRIDE + ec;
        const float* v3 = Vb + (size_t)((t3 << 6) + 2 * rp) * ROWSTRIDE + ec;
        float4 ka2 = *(const float4*)k2, kb2 = *(const float4*)(k2 + 4);
        float4 ka3 = *(const float4*)k3, kb3 = *(const float4*)(k3 + 4);
        float4 va2 = *(const float4*)v2, vb2 = *(const float4*)(v2 + ROWSTRIDE);
        float4 va3 = *(const float4*)v3, vb3 = *(const float4*)(v3 + ROWSTRIDE);

        compute2(pb, base);
        if (base + 1 < ntiles) compute2(pb + 1, base + 1);

        if (base + 2 < ntiles) { stageK(pb ^ 2, ka2, kb2); stageV(pb ^ 2, va2, vb2); }
        if (base + 3 < ntiles) { stageK((pb ^ 2) + 1, ka3, kb3); stageV((pb ^ 2) + 1, va3, vb3); }
        sbar();
    }

    // ---- combine partial O across groups (Ob overlays Ks; safe after barrier) ----
    if (g == 1) {
#pragma unroll
        for (int r = 0; r < 4; ++r) {
            const int row = 16 * wg + quad * 4 + r;
#pragma unroll
            for (int j = 0; j < 4; ++j)
                Ob[row * 65 + 16 * j + l15] = oacc[j][r];
        }
    }
    sbar();
    if (g == 0) {
#pragma unroll
        for (int r = 0; r < 4; ++r) {
            const int row = 16 * wg + quad * 4 + r;
            float* op = outV + ((size_t)b * L_DIM + q0 + row) * ROWSTRIDE + h * 64 + l15;
#pragma unroll
            for (int j = 0; j < 4; ++j)
                op[16 * j] = oacc[j][r] + Ob[row * 65 + 16 * j + l15];
        }
    }

    // ---- zero-fill SA above the diagonal tile (d_out is poisoned) ----
    {
        const int z0 = ntiles << 6;
        const int zr = t >> 3;               // 64 rows, 8 threads/row
        float* rowp = saBase + (size_t)(q0 + zr) * L_DIM;
        const float4 zf = {0.f, 0.f, 0.f, 0.f};
        for (int s = z0 + (t & 7) * 4; s < L_DIM; s += 32)
            *(float4*)(rowp + s) = zf;
    }
}

extern "C" void kernel_launch(void* const* d_in, const int* in_sizes, int n_in,
                              void* d_out, int out_size, void* d_ws, size_t ws_size,
                              hipStream_t stream) {
    const float* Q  = (const float*)d_in[0];
    const float* K  = (const float*)d_in[1];
    const float* Vv = (const float*)d_in[2];
    float* out   = (float*)d_out;
    float* outV  = out;                                       // [B,L,H,E]
    float* outSA = out + (size_t)2 * L_DIM * H_DIM * 64;      // [B,H,L,S]
    float* lse   = (float*)d_ws;                              // [2*8*2048] fp32 = 128 KB

    attn_lse9<<<dim3(512), dim3(256), 0, stream>>>(Q, K, lse);
    attn_pv9<<<dim3(512), dim3(512), 0, stream>>>(Q, K, Vv, outV, outSA, lse);
}

// Round 9
// 340.983 us; speedup vs baseline: 1.0460x; 1.0399x over previous
//
#include <hip/hip_runtime.h>
#include <math.h>

// B=2, L=2048, H=8, E=64. Outputs: V [B,L,H,E] then SA [B,H,L,S], fp32.
#define L_DIM 2048
#define H_DIM 8
#define ROWSTRIDE 512                 // H*E floats between consecutive l
#define NT 512
// 0.125 * log2(e): scores computed in log2 domain -> raw v_exp_f32 for softmax
#define QSCALE 0.18033688011112042f
#define FLT_BIG 3.402823466e+38f

typedef __attribute__((ext_vector_type(8))) short short8;
typedef __attribute__((ext_vector_type(4))) float floatx4;

__device__ __forceinline__ float fexp2(float x) {
#if __has_builtin(__builtin_amdgcn_exp2f)
    return __builtin_amdgcn_exp2f(x);   // raw v_exp_f32
#else
    return exp2f(x);
#endif
}

__device__ __forceinline__ float flog2(float x) {
#if __has_builtin(__builtin_amdgcn_logf)
    return __builtin_amdgcn_logf(x);    // raw v_log_f32 (base-2)
#else
    return log2f(x);
#endif
}

// packed fp32x2 -> bf16x2 (RNE), one VALU op for two elements
__device__ __forceinline__ unsigned int cvtpk(float lo, float hi) {
    unsigned int r;
    asm("v_cvt_pk_bf16_f32 %0, %1, %2" : "=v"(r) : "v"(lo), "v"(hi));
    return r;
}

__device__ __forceinline__ short8 pack8(float4 a, float4 b) {
    union { unsigned int u[4]; short8 v; } pk;
    pk.u[0] = cvtpk(a.x, a.y); pk.u[1] = cvtpk(a.z, a.w);
    pk.u[2] = cvtpk(b.x, b.y); pk.u[3] = cvtpk(b.z, b.w);
    return pk.v;
}

__device__ __forceinline__ short8 pack8q(float4 a, float4 b) {
    union { unsigned int u[4]; short8 v; } pk;
    pk.u[0] = cvtpk(a.x * QSCALE, a.y * QSCALE);
    pk.u[1] = cvtpk(a.z * QSCALE, a.w * QSCALE);
    pk.u[2] = cvtpk(b.x * QSCALE, b.y * QSCALE);
    pk.u[3] = cvtpk(b.z * QSCALE, b.w * QSCALE);
    return pk.v;
}

// Swizzled short-index within a [64][64] bf16 tile. Rows are 128B = 8 x 16B
// blocks; phys block = logical block ^ (row&7). Preserves col&7 (b32/b128
// alignment holds). Bijective per row.
__device__ __forceinline__ int swz(int row, int col) {
    return (row << 6) + ((((col >> 3) ^ (row & 7)) << 3) | (col & 7));
}

// Barrier WITHOUT vmcnt(0) drain (essential with in-flight zero/SA stores:
// __syncthreads' vmcnt(0) would re-serialize store drain with compute each
// phase). LDS producer/consumer hazards are lgkm-tracked; prefetch-load
// vmcnt waits are compiler-inserted at their stage-write uses.
__device__ __forceinline__ void sbar() {
    asm volatile("s_waitcnt lgkmcnt(0)" ::: "memory");
    __builtin_amdgcn_s_barrier();
    asm volatile("" ::: "memory");
}

// 512 blocks x 512 threads (8 waves). XCD = bid&7 hosts head h=bid&7 (both
// batches: K+V = 2MB, L2-resident). Decode keeps co-resident q-tile pairs
// complementary under both (m,m+1) and (m,m+32) placements (round 5).
// ROUND 9 (on the round-5 best): the ~130MB above-diagonal zero-fill moves
// from a serial post-compute tail (~20us, store pipe otherwise idle during
// compute) into the phase loops: block (h,b,qt) zero-fills the region of
// COMPLEMENT tile T=31-qt (coverage exact; zero volume 4096*qt floats is
// proportional to this block's phase count -> constant 2 float4/thread/phase).
// Slices are issued AFTER each phase's prefetch loads so they stay YOUNGER in
// vmcnt order (vmcnt retires in order; staging waits never block on store
// drain). Barriers are sbar() so stores float across phases.
__global__ __launch_bounds__(NT, 4)
void attn_mfma10(const float* __restrict__ Q, const float* __restrict__ K,
                 const float* __restrict__ Vv, float* __restrict__ outV,
                 float* __restrict__ outSA)
{
    __shared__ __align__(16) unsigned char smem[74752];
    unsigned short* Ks = (unsigned short*)(smem);           // [4 buf][64][64] swz, row-permuted s
    unsigned short* Vt = (unsigned short*)(smem + 32768);   // [4 buf][64][64] swz, row=e col=s
    unsigned short* Ps = (unsigned short*)(smem + 65536);   // [64][64] swz
    float* Ml = (float*)(smem + 73728);                     // [2][64]
    float* Ll = (float*)(smem + 74240);                     // [2][64]
    float* Ob = (float*)(smem);                             // [64][65] fp32, overlays Ks

    const int t    = threadIdx.x;
    const int lane = t & 63;
    const int w    = t >> 6;           // wave 0..7
    const int g    = w >> 2;           // s-column group: cols [32g, 32g+32)
    const int wg   = w & 3;            // wave-in-group: q-rows 16wg..16wg+15
    const int l15  = lane & 15;
    const int quad = lane >> 4;
    const int gc   = g << 5;           // group column base within tile

    const int bid = blockIdx.x;
    const int h   = bid & 7;
    const int b   = (bid >> 3) & 1;
    const int kk  = bid >> 4;                   // 0..31
    const int qm  = (kk < 16) ? kk : (47 - kk); // bijective, qm(k)+qm(k+16)=31
    const int qt  = b ? (31 - qm) : qm;
    const int q0  = qt << 6;
    const int ntiles = qt + 1;
    const int nphase = (ntiles + 1) >> 1;

    const float* Qb = Q  + (size_t)b * L_DIM * ROWSTRIDE + h * 64;
    const float* Kb = K  + (size_t)b * L_DIM * ROWSTRIDE + h * 64;
    const float* Vb = Vv + (size_t)b * L_DIM * ROWSTRIDE + h * 64;
    float* saBase = outSA + (size_t)(b * H_DIM + h) * L_DIM * L_DIM;

    // ---- zero-fill state: complement tile Tz = 31-qt, zn = 2*qt float4/thread.
    // Thread t covers row (t>>3) of [64*Tz .. 64*Tz+64), float4 cols
    // (t&7) + 8*zj for zj in [0, 2*qt)  -> exact tiling of 64 x 64*qt floats.
    const int Tz = 31 - qt;
    const int zn = 2 * qt;
    int zj = 0;
    float* zb = saBase + (size_t)(64 * Tz + (t >> 3)) * L_DIM + 64 * (Tz + 1)
                + ((t & 7) << 2);
    const float4 zf4 = {0.f, 0.f, 0.f, 0.f};

    // ---- K staging map: thread handles logical s-row sr, 8 e at col sc.
    // Row-permute within each 32-row group: kq=sr&31 -> phys (kq&1)*16+(kq>>1),
    // so frag jj, lane l15 reads s = gc + 2*l15 + jj.
    const int sr = t >> 3, sc = (t & 7) << 3;
    const int kq = sr & 31;
    const int kpr = (sr & 32) | ((kq & 1) << 4) | (kq >> 1);
    const int kswz = swz(kpr, sc);     // 16B-aligned short8 dest

    // ---- V staging map: thread handles s-rows {2rp, 2rp+1}, 4 e at ec.
    const int rp = t >> 4, ec = (t & 15) << 2;
    const int vswz0 = swz(ec + 0, 2 * rp);   // b32-aligned (col even)
    const int vswz1 = swz(ec + 1, 2 * rp);
    const int vswz2 = swz(ec + 2, 2 * rp);
    const int vswz3 = swz(ec + 3, 2 * rp);

    auto stageK = [&](int bufi, float4 f0, float4 f1) {
        *(short8*)&Ks[(bufi << 12) + kswz] = pack8(f0, f1);
    };
    auto stageV = [&](int bufi, float4 a, float4 bb) {
        unsigned short* Vn = Vt + (bufi << 12);
        *(unsigned int*)&Vn[vswz0] = cvtpk(a.x, bb.x);
        *(unsigned int*)&Vn[vswz1] = cvtpk(a.y, bb.y);
        *(unsigned int*)&Vn[vswz2] = cvtpk(a.z, bb.z);
        *(unsigned int*)&Vn[vswz3] = cvtpk(a.w, bb.w);
    };
    // 2 float4 zero stores per phase; issued after that phase's prefetch
    // loads (younger in vmcnt order) so staging never waits on store drain.
    auto zslice = [&]() {
        if (zj < zn) {
            *(float4*)(zb + (zj << 5)) = zf4; ++zj;
            if (zj < zn) { *(float4*)(zb + (zj << 5)) = zf4; ++zj; }
        }
    };

    // ---- Q fragments straight from global (scale folded), once per block ----
    short8 aQ0, aQ1;
    {
        const float* qsrc = Qb + (size_t)(q0 + 16 * wg + l15) * ROWSTRIDE + quad * 8;
        aQ0 = pack8q(*(const float4*)(qsrc),      *(const float4*)(qsrc + 4));
        aQ1 = pack8q(*(const float4*)(qsrc + 32), *(const float4*)(qsrc + 36));
    }

    // =================== PASS 1: row max & denom (per-lane online) ===================
    float m_r[4], l_r[4];
#pragma unroll
    for (int r = 0; r < 4; ++r) { m_r[r] = -FLT_BIG; l_r[r] = 0.f; }

    auto compute1 = [&](int bufi, int st) {
        const unsigned short* Kc = Ks + (bufi << 12);
        floatx4 d0, d1;
        {
            short8 b0 = *(const short8*)&Kc[swz(gc + l15, quad * 8)];
            short8 b1 = *(const short8*)&Kc[swz(gc + l15, 32 + quad * 8)];
            floatx4 acc = {0.f, 0.f, 0.f, 0.f};
            acc = __builtin_amdgcn_mfma_f32_16x16x32_bf16(aQ0, b0, acc, 0, 0, 0);
            acc = __builtin_amdgcn_mfma_f32_16x16x32_bf16(aQ1, b1, acc, 0, 0, 0);
            d0 = acc;
        }
        {
            short8 b0 = *(const short8*)&Kc[swz(gc + 16 + l15, quad * 8)];
            short8 b1 = *(const short8*)&Kc[swz(gc + 16 + l15, 32 + quad * 8)];
            floatx4 acc = {0.f, 0.f, 0.f, 0.f};
            acc = __builtin_amdgcn_mfma_f32_16x16x32_bf16(aQ0, b0, acc, 0, 0, 0);
            acc = __builtin_amdgcn_mfma_f32_16x16x32_bf16(aQ1, b1, acc, 0, 0, 0);
            d1 = acc;
        }
        if (st == qt) {          // diagonal tile: mask (s = s0+gc+2*l15 {+1})
            const int scol = (st << 6) + gc + 2 * l15;
#pragma unroll
            for (int r = 0; r < 4; ++r) {
                const int lrow = q0 + 16 * wg + quad * 4 + r;
                float v0 = (scol     <= lrow) ? d0[r] : -INFINITY;
                float v1 = (scol + 1 <= lrow) ? d1[r] : -INFINITY;
                const float mnew = fmaxf(m_r[r], fmaxf(v0, v1));  // finite
                float es = fexp2(v0 - mnew) + fexp2(v1 - mnew);   // exp2(-inf)=0
                l_r[r] = l_r[r] * fexp2(m_r[r] - mnew) + es;
                m_r[r] = mnew;
            }
        } else {
#pragma unroll
            for (int r = 0; r < 4; ++r) {
                float v0 = d0[r], v1 = d1[r];
                const float mnew = fmaxf(m_r[r], fmaxf(v0, v1));
                float es = fexp2(v0 - mnew) + fexp2(v1 - mnew);
                l_r[r] = l_r[r] * fexp2(m_r[r] - mnew) + es;
                m_r[r] = mnew;
            }
        }
    };

    {   // prologue: stage tiles 0 and 1 (dup tile 0 if ntiles==1)
        const int t1 = (ntiles > 1) ? 1 : 0;
        const float* k0 = Kb + (size_t)sr * ROWSTRIDE + sc;
        const float* k1 = Kb + (size_t)((t1 << 6) + sr) * ROWSTRIDE + sc;
        stageK(0, *(const float4*)k0, *(const float4*)(k0 + 4));
        stageK(1, *(const float4*)k1, *(const float4*)(k1 + 4));
    }
    sbar();

    for (int ph = 0; ph < nphase; ++ph) {
        const int base = ph << 1;
        const int pb   = (ph & 1) << 1;
        // prefetch next pair into regs (clamped addresses on the tail)
        const int t2 = (base + 2 < ntiles) ? base + 2 : ntiles - 1;
        const int t3 = (base + 3 < ntiles) ? base + 3 : ntiles - 1;
        const float* k2 = Kb + (size_t)((t2 << 6) + sr) * ROWSTRIDE + sc;
        const float* k3 = Kb + (size_t)((t3 << 6) + sr) * ROWSTRIDE + sc;
        float4 a2 = *(const float4*)k2, b2 = *(const float4*)(k2 + 4);
        float4 a3 = *(const float4*)k3, b3 = *(const float4*)(k3 + 4);

        compute1(pb, base);
        if (base + 1 < ntiles) compute1(pb + 1, base + 1);

        zslice();   // zero-fill slice (younger than this phase's loads)

        if (base + 2 < ntiles) stageK(pb ^ 2, a2, b2);
        if (base + 3 < ntiles) stageK((pb ^ 2) + 1, a3, b3);
        sbar();
    }

    // ---- merge (m,l) across the 16 lanes owning this row's s-columns ----
#pragma unroll
    for (int r = 0; r < 4; ++r) {
#pragma unroll
        for (int mk = 1; mk < 16; mk <<= 1) {
            float mo = __shfl_xor(m_r[r], mk);
            float lo = __shfl_xor(l_r[r], mk);
            float mn = fmaxf(m_r[r], mo);      // finite always
            l_r[r] = l_r[r] * fexp2(m_r[r] - mn) + lo * fexp2(mo - mn);
            m_r[r] = mn;
        }
    }

    // ---- combine across the two s-column groups via LDS ----
    if (l15 == 0) {
#pragma unroll
        for (int r = 0; r < 4; ++r) {
            const int row = 16 * wg + quad * 4 + r;
            Ml[g * 64 + row] = m_r[r];
            Ll[g * 64 + row] = l_r[r];
        }
    }
    {   // pass-2 prologue: stage K and V^T tiles 0,1 (overlaps m/l combine)
        const int t1 = (ntiles > 1) ? 1 : 0;
        const float* k0 = Kb + (size_t)sr * ROWSTRIDE + sc;
        const float* k1 = Kb + (size_t)((t1 << 6) + sr) * ROWSTRIDE + sc;
        stageK(0, *(const float4*)k0, *(const float4*)(k0 + 4));
        stageK(1, *(const float4*)k1, *(const float4*)(k1 + 4));
        const float* v0p = Vb + (size_t)(2 * rp) * ROWSTRIDE + ec;
        const float* v1p = Vb + (size_t)((t1 << 6) + 2 * rp) * ROWSTRIDE + ec;
        stageV(0, *(const float4*)v0p, *(const float4*)(v0p + ROWSTRIDE));
        stageV(1, *(const float4*)v1p, *(const float4*)(v1p + ROWSTRIDE));
    }
    sbar();

    // c_r = m_final + log2(l_final): p = exp2(v - c_r), normalization folded
    float c_r[4];
#pragma unroll
    for (int r = 0; r < 4; ++r) {
        const int row = 16 * wg + quad * 4 + r;
        float m0 = Ml[row], m1 = Ml[64 + row];
        float l0 = Ll[row], l1 = Ll[64 + row];
        float mf = fmaxf(m0, m1);              // finite (never -inf)
        float lf = l0 * fexp2(m0 - mf) + l1 * fexp2(m1 - mf);  // 0 contrib for all-masked group
        c_r[r] = mf + flog2(lf);
    }

    // =================== PASS 2: SA write + PV ===================
    floatx4 oacc[4];
#pragma unroll
    for (int j = 0; j < 4; ++j) oacc[j] = (floatx4){0.f, 0.f, 0.f, 0.f};

    auto compute2 = [&](int bufi, int st) {
        const unsigned short* Kc = Ks + (bufi << 12);
        const unsigned short* Vc = Vt + (bufi << 12);
        floatx4 d0, d1;
        {
            short8 b0 = *(const short8*)&Kc[swz(gc + l15, quad * 8)];
            short8 b1 = *(const short8*)&Kc[swz(gc + l15, 32 + quad * 8)];
            floatx4 acc = {0.f, 0.f, 0.f, 0.f};
            acc = __builtin_amdgcn_mfma_f32_16x16x32_bf16(aQ0, b0, acc, 0, 0, 0);
            acc = __builtin_amdgcn_mfma_f32_16x16x32_bf16(aQ1, b1, acc, 0, 0, 0);
            d0 = acc;
        }
        {
            short8 b0 = *(const short8*)&Kc[swz(gc + 16 + l15, quad * 8)];
            short8 b1 = *(const short8*)&Kc[swz(gc + 16 + l15, 32 + quad * 8)];
            floatx4 acc = {0.f, 0.f, 0.f, 0.f};
            acc = __builtin_amdgcn_mfma_f32_16x16x32_bf16(aQ0, b0, acc, 0, 0, 0);
            acc = __builtin_amdgcn_mfma_f32_16x16x32_bf16(aQ1, b1, acc, 0, 0, 0);
            d1 = acc;
        }
        const int s0 = st << 6;
        const int scol = s0 + gc + 2 * l15;
        if (st == qt) {          // diagonal tile: masked path
#pragma unroll
            for (int r = 0; r < 4; ++r) {
                const int lrow = q0 + 16 * wg + quad * 4 + r;
                const float cr = c_r[r];
                float p0 = (scol     <= lrow) ? fexp2(d0[r] - cr) : 0.0f;
                float p1 = (scol + 1 <= lrow) ? fexp2(d1[r] - cr) : 0.0f;
                float2 pr; pr.x = p0; pr.y = p1;
                *(float2*)(saBase + (size_t)lrow * L_DIM + scol) = pr;
                *(unsigned int*)&Ps[swz(16 * wg + quad * 4 + r, gc + 2 * l15)] = cvtpk(p0, p1);
            }
        } else {                 // interior tile: no masking
#pragma unroll
            for (int r = 0; r < 4; ++r) {
                const int lrow = q0 + 16 * wg + quad * 4 + r;
                const float cr = c_r[r];
                float p0 = fexp2(d0[r] - cr);
                float p1 = fexp2(d1[r] - cr);
                float2 pr; pr.x = p0; pr.y = p1;
                *(float2*)(saBase + (size_t)lrow * L_DIM + scol) = pr;
                *(unsigned int*)&Ps[swz(16 * wg + quad * 4 + r, gc + 2 * l15)] = cvtpk(p0, p1);
            }
        }
        // PV over this group's 32 s-cols: Ps rows/col-halves are wave-private;
        // compiler's in-order lgkmcnt covers the RAW.
        short8 aP = *(const short8*)&Ps[swz(16 * wg + l15, gc + quad * 8)];
#pragma unroll
        for (int j = 0; j < 4; ++j) {
            short8 bv = *(const short8*)&Vc[swz(16 * j + l15, gc + quad * 8)];
            oacc[j] = __builtin_amdgcn_mfma_f32_16x16x32_bf16(aP, bv, oacc[j], 0, 0, 0);
        }
    };

    for (int ph = 0; ph < nphase; ++ph) {
        const int base = ph << 1;
        const int pb   = (ph & 1) << 1;
        const int t2 = (base + 2 < ntiles) ? base + 2 : ntiles - 1;
        const int t3 = (base + 3 < ntiles) ? base + 3 : ntiles - 1;
        const float* k2 = Kb + (size_t)((t2 << 6) + sr) * ROWSTRIDE + sc;
        const float* k3 = Kb + (size_t)((t3 << 6) + sr) * ROWSTRIDE + sc;
        const float* v2 = Vb + (size_t)((t2 << 6) + 2 * rp) * ROWSTRIDE + ec;
        const float* v3 = Vb + (size_t)((t3 << 6) + 2 * rp) * ROWSTRIDE + ec;
        float4 ka2 = *(const float4*)k2, kb2 = *(const float4*)(k2 + 4);
        float4 ka3 = *(const float4*)k3, kb3 = *(const float4*)(k3 + 4);
        float4 va2 = *(const float4*)v2, vb2 = *(const float4*)(v2 + ROWSTRIDE);
        float4 va3 = *(const float4*)v3, vb3 = *(const float4*)(v3 + ROWSTRIDE);

        compute2(pb, base);
        if (base + 1 < ntiles) compute2(pb + 1, base + 1);

        zslice();   // zero-fill slice (younger than this phase's loads)

        if (base + 2 < ntiles) { stageK(pb ^ 2, ka2, kb2); stageV(pb ^ 2, va2, vb2); }
        if (base + 3 < ntiles) { stageK((pb ^ 2) + 1, ka3, kb3); stageV((pb ^ 2) + 1, va3, vb3); }
        sbar();
    }

    // ---- drain any remaining zero slices (rare: only if phases < qt) ----
    while (zj < zn) { *(float4*)(zb + (zj << 5)) = zf4; ++zj; }

    // ---- combine partial O across groups (Ob overlays Ks; safe after barrier) ----
    if (g == 1) {
#pragma unroll
        for (int r = 0; r < 4; ++r) {
            const int row = 16 * wg + quad * 4 + r;
#pragma unroll
            for (int j = 0; j < 4; ++j)
                Ob[row * 65 + 16 * j + l15] = oacc[j][r];
        }
    }
    sbar();
    if (g == 0) {
#pragma unroll
        for (int r = 0; r < 4; ++r) {
            const int row = 16 * wg + quad * 4 + r;
            float* op = outV + ((size_t)b * L_DIM + q0 + row) * ROWSTRIDE + h * 64 + l15;
#pragma unroll
            for (int j = 0; j < 4; ++j)
                op[16 * j] = oacc[j][r] + Ob[row * 65 + 16 * j + l15];
        }
    }
}

extern "C" void kernel_launch(void* const* d_in, const int* in_sizes, int n_in,
                              void* d_out, int out_size, void* d_ws, size_t ws_size,
                              hipStream_t stream) {
    const float* Q  = (const float*)d_in[0];
    const float* K  = (const float*)d_in[1];
    const float* Vv = (const float*)d_in[2];
    float* out   = (float*)d_out;
    float* outV  = out;                                       // [B,L,H,E]
    float* outSA = out + (size_t)2 * L_DIM * H_DIM * 64;      // [B,H,L,S]

    dim3 grid(512);   // complementary q-tile pairs (dual-robust decode)
    dim3 block(NT);
    attn_mfma10<<<grid, block, 0, stream>>>(Q, K, Vv, outV, outSA);
}